// Round 3
// baseline (1096.336 us; speedup 1.0000x reference)
//
#include <hip/hip_runtime.h>
#include <hip/hip_bf16.h>
#include <stdint.h>

#define NN 50000
#define NE 800000
#define F 128
#define NCLS 16
#define NB 196          // ceil(NN/256) buckets

typedef __attribute__((ext_vector_type(8))) short short8;
typedef __attribute__((ext_vector_type(4))) float f32x4;
typedef __attribute__((ext_vector_type(4))) unsigned int uint4v;

// ---- ws byte offsets ----
#define OB_COLSUM    0u          // float[128]
#define OB_BHIST     512u        // int[196]
#define OB_BBASE     1312u       // int[196]
#define OB_BCUR      2112u       // int[196]
#define OB_ROWSTART  4096u       // int[50001]
#define OB_INVDEG    208896u     // float[50000]
#define OB_PAIRS     409600u     // u32[800000]
#define OB_SRCS16    3605504u    // u16[800000]
#define OB_WT        5205504u    // bf16 6*16384 (layout L)
#define OB_XB        5406720u    // bf16 [NN][128] layout L (doubles as HB2)
#define OB_HB1       18206720u
#define OB_NB        31006720u   // ends 43806720

// ---- swizzled bf16 feature layout L ----
// element (row,k) at byte: row*256 + 16*(chunk(k) ^ (row&15)) + inchunk(k)
// chunk(k) = (k>>5)*4 | ((k>>2)&3); inchunk = ((k>>4)&1)*8 + (k&3)*2
__device__ __forceinline__ uint32_t swz_off(uint32_t row, uint32_t k) {
    uint32_t c = ((k >> 5) << 2) | ((k >> 2) & 3u);
    uint32_t b = (((k >> 4) & 1u) << 3) | ((k & 3u) << 1);
    return (row << 8) + (((c ^ (row & 15u)) << 4) | b);
}

__device__ __forceinline__ float bf_lo(uint32_t d) { return __uint_as_float(d << 16); }
__device__ __forceinline__ float bf_hi(uint32_t d) { return __uint_as_float(d & 0xffff0000u); }
__device__ __forceinline__ uint32_t pack_bf2(float a, float b) {
    __hip_bfloat16 l = __float2bfloat16(a), h = __float2bfloat16(b);
    return ((uint32_t)(*(uint16_t*)&h) << 16) | (uint32_t)(*(uint16_t*)&l);
}

// ====== convert x to bf16 layout L (float4/thread) + bucket histogram ======
__global__ __launch_bounds__(256) void convert_x_hist(const float* __restrict__ x,
                                                      const int* __restrict__ dst,
                                                      uint8_t* __restrict__ xb,
                                                      int* __restrict__ bhist) {
    int t = blockIdx.x * 256 + threadIdx.x;          // NN*32 quad-slots
    if (t < NE) atomicAdd(&bhist[dst[t] >> 8], 1);
    uint32_t row = (uint32_t)t >> 5;
    uint32_t q = (uint32_t)t & 31u;                  // 4-k group
    float4 v = *(const float4*)(x + row * F + q * 4);
    uint32_t c = ((q >> 3) << 2) | (q & 3u);
    uint32_t hi = (q >> 2) & 1u;
    uint2 pk;
    pk.x = pack_bf2(v.x, v.y);
    pk.y = pack_bf2(v.z, v.w);
    *(uint2*)(xb + (row << 8) + (((c ^ (row & 15u)) << 4) | (hi << 3))) = pk;
}

// transpose + convert weights: Wt[n][k] = W[k][n], layout L on (n,k)
__global__ __launch_bounds__(256) void prep_w(const float* __restrict__ w0, const float* __restrict__ w1,
                                              const float* __restrict__ w2, const float* __restrict__ w3,
                                              const float* __restrict__ w4, const float* __restrict__ w5,
                                              uint8_t* __restrict__ wt) {
    int m = blockIdx.y;
    const float* w = m == 0 ? w0 : m == 1 ? w1 : m == 2 ? w2 : m == 3 ? w3 : m == 4 ? w4 : w5;
    int t = blockIdx.x * 256 + threadIdx.x;          // 8192 pair-slots
    int n = t >> 6;
    int k0 = (t & 63) << 1;
    uint32_t pk = pack_bf2(w[k0 * F + n], w[(k0 + 1) * F + n]);
    *(uint32_t*)(wt + (uint32_t)m * 32768u + swz_off((uint32_t)n, (uint32_t)k0)) = pk;
}

// ====== bucket base scan (196 values, 1 block) ======
__global__ __launch_bounds__(256) void bucket_scan(const int* __restrict__ bhist,
                                                   int* __restrict__ bbase,
                                                   int* __restrict__ bcur,
                                                   int* __restrict__ row_start) {
    __shared__ int s[256];
    int t = threadIdx.x;
    int v = (t < NB) ? bhist[t] : 0;
    s[t] = v;
    __syncthreads();
    for (int off = 1; off < 256; off <<= 1) {
        int u = (t >= off) ? s[t - off] : 0;
        __syncthreads();
        s[t] += u;
        __syncthreads();
    }
    int excl = s[t] - v;
    if (t < NB) { bbase[t] = excl; bcur[t] = excl; }
    if (t == 0) row_start[NN] = NE;
}

// ====== pass A: scatter packed (src | localrow<<16) into bucket streams ======
__global__ __launch_bounds__(256) void pass_a(const int* __restrict__ src,
                                              const int* __restrict__ dst,
                                              int* __restrict__ bcur,
                                              uint32_t* __restrict__ pairs) {
    int e = blockIdx.x * 256 + threadIdx.x;
    if (e >= NE) return;
    int sv = src[e], dv = dst[e];
    int pos = atomicAdd(&bcur[dv >> 8], 1);
    pairs[pos] = (uint32_t)sv | (((uint32_t)dv & 255u) << 16);
}

// ====== pass B: per-bucket count/scan, emit row_start+inv_deg+srcs16 ======
__global__ __launch_bounds__(256) void pass_b(const uint32_t* __restrict__ pairs,
                                              const int* __restrict__ bbase,
                                              int* __restrict__ row_start,
                                              float* __restrict__ inv_deg,
                                              unsigned short* __restrict__ srcs) {
    __shared__ int cnt[256];
    __shared__ int s[256];
    __shared__ int cur[256];
    int b = blockIdx.x, t = threadIdx.x;
    int start = bbase[b];
    int end = (b == NB - 1) ? NE : bbase[b + 1];
    cnt[t] = 0;
    __syncthreads();
    for (int i = start + t; i < end; i += 256)
        atomicAdd(&cnt[pairs[i] >> 16], 1);
    __syncthreads();
    int v = cnt[t];
    s[t] = v;
    __syncthreads();
    for (int off = 1; off < 256; off <<= 1) {
        int u = (t >= off) ? s[t - off] : 0;
        __syncthreads();
        s[t] += u;
        __syncthreads();
    }
    int excl = s[t] - v;
    cur[t] = start + excl;
    int row = (b << 8) + t;
    if (row < NN) {
        row_start[row] = start + excl;
        inv_deg[row] = 1.0f / (float)(v > 1 ? v : 1);
    }
    __syncthreads();
    for (int i = start + t; i < end; i += 256) {
        uint32_t p = pairs[i];
        int pos = atomicAdd(&cur[p >> 16], 1);
        srcs[pos] = (unsigned short)(p & 0xffffu);
    }
}

// ====== aggregate: one wave per node, 2 edges/iter, dwordx2 gathers ======
__global__ __launch_bounds__(256) void aggregate_b(
        const uint8_t* __restrict__ hb, const int* __restrict__ row_start,
        const unsigned short* __restrict__ srcs, const float* __restrict__ inv_deg,
        uint8_t* __restrict__ nb) {
    int node = blockIdx.x * 4 + (threadIdx.x >> 6);
    int l = threadIdx.x & 63;
    int half = l >> 5;
    uint32_t sub = (uint32_t)(l & 31);
    uint32_t c_lin = sub & 15u;
    uint32_t boff = (sub >> 4) << 3;
    int e0 = row_start[node], e1 = row_start[node + 1];
    float a0 = 0.f, a1 = 0.f, a2 = 0.f, a3 = 0.f;

#define LDROW(S) (*(const uint2*)(hb + ((uint32_t)(S) << 8) + (((c_lin ^ ((uint32_t)(S) & 15u)) << 4) | boff)))
    int e = e0 + half;
    for (; e + 6 < e1; e += 8) {
        uint32_t s0 = srcs[e], s1 = srcs[e + 2], s2 = srcs[e + 4], s3 = srcs[e + 6];
        uint2 d0 = LDROW(s0);
        uint2 d1 = LDROW(s1);
        uint2 d2 = LDROW(s2);
        uint2 d3 = LDROW(s3);
        a0 += bf_lo(d0.x) + bf_lo(d1.x) + bf_lo(d2.x) + bf_lo(d3.x);
        a1 += bf_hi(d0.x) + bf_hi(d1.x) + bf_hi(d2.x) + bf_hi(d3.x);
        a2 += bf_lo(d0.y) + bf_lo(d1.y) + bf_lo(d2.y) + bf_lo(d3.y);
        a3 += bf_hi(d0.y) + bf_hi(d1.y) + bf_hi(d2.y) + bf_hi(d3.y);
    }
    for (; e < e1; e += 2) {
        uint32_t s0 = srcs[e];
        uint2 d0 = LDROW(s0);
        a0 += bf_lo(d0.x); a1 += bf_hi(d0.x); a2 += bf_lo(d0.y); a3 += bf_hi(d0.y);
    }
#undef LDROW
    // combine the two edge-halves
    a0 += __shfl_xor(a0, 32);
    a1 += __shfl_xor(a1, 32);
    a2 += __shfl_xor(a2, 32);
    a3 += __shfl_xor(a3, 32);
    if (half == 0) {
        float idg = inv_deg[node];
        uint2 pk;
        pk.x = pack_bf2(a0 * idg, a1 * idg);
        pk.y = pack_bf2(a2 * idg, a3 * idg);
        *(uint2*)(nb + ((uint32_t)node << 8) +
                  (((c_lin ^ ((uint32_t)node & 15u)) << 4) | boff)) = pk;
    }
}

// ====== MFMA GEMM: hout = relu(As@Ws + An@Wn + b); optional colsum fuse ======
__global__ __launch_bounds__(256) void gemm_mfma(
        const uint8_t* __restrict__ a_self, const uint8_t* __restrict__ a_neigh,
        const uint8_t* __restrict__ wt_self, const uint8_t* __restrict__ wt_neigh,
        const float* __restrict__ bias, uint8_t* __restrict__ hout,
        float* colsum) {
    __shared__ uint4v As4[1024];   // 16 KB
    __shared__ uint4v Ws4[2048];   // 32 KB
    __shared__ float cs[128];
    int tid = threadIdx.x;
    int lane = tid & 63, wave = tid >> 6;
    int rl = lane & 15, g = lane >> 4;
    int row0 = blockIdx.x * 64;

    f32x4 acc[8];
    f32x4 z = {0.f, 0.f, 0.f, 0.f};
#pragma unroll
    for (int nt = 0; nt < 8; ++nt) acc[nt] = z;

    const char* AsB = (const char*)As4;
    const char* WsB = (const char*)Ws4;

#pragma unroll
    for (int pass = 0; pass < 2; ++pass) {
        if (pass) __syncthreads();
        const uint4v* ga = (const uint4v*)((pass ? a_neigh : a_self) + (size_t)row0 * 256);
        const uint4v* gw = (const uint4v*)(pass ? wt_neigh : wt_self);
#pragma unroll
        for (int i = 0; i < 4; ++i) As4[tid + i * 256] = ga[tid + i * 256];
#pragma unroll
        for (int i = 0; i < 8; ++i) Ws4[tid + i * 256] = gw[tid + i * 256];
        __syncthreads();
#pragma unroll
        for (int ks = 0; ks < 4; ++ks) {
            int chunk = ((ks << 2) | g) ^ rl;
            short8 a = *(const short8*)(AsB + ((wave * 16 + rl) << 8) + (chunk << 4));
#pragma unroll
            for (int nt = 0; nt < 8; ++nt) {
                short8 bb = *(const short8*)(WsB + ((nt * 16 + rl) << 8) + (chunk << 4));
                acc[nt] = __builtin_amdgcn_mfma_f32_16x16x32_bf16(a, bb, acc[nt], 0, 0, 0);
            }
        }
    }

    bool doCol = (colsum != nullptr);
    if (doCol) {
        if (tid < 128) cs[tid] = 0.f;
        __syncthreads();
    }
#pragma unroll
    for (int nt = 0; nt < 8; ++nt) {
        int col = nt * 16 + rl;
        float bv = bias[col];
        float rsum = 0.f;
#pragma unroll
        for (int i = 0; i < 4; ++i) {
            int row = row0 + wave * 16 + g * 4 + i;
            if (row < NN) {
                float v = fmaxf(acc[nt][i] + bv, 0.f);
                rsum += v;
                *(__hip_bfloat16*)(hout + swz_off((uint32_t)row, (uint32_t)col)) =
                    __float2bfloat16(v);
            }
        }
        if (doCol) atomicAdd(&cs[col], rsum);
    }
    if (doCol) {
        __syncthreads();
        if (tid < 128) atomicAdd(&colsum[tid], cs[tid]);
    }
}

__global__ __launch_bounds__(128) void head_kernel(const float* __restrict__ colsum,
                                                   const float* __restrict__ w_head,
                                                   const float* __restrict__ b_head,
                                                   float* __restrict__ out) {
    __shared__ float pls[F];
    int t = threadIdx.x;
    float p = colsum[t] * (1.0f / (float)NN);
    pls[t] = p;
    out[NCLS + t] = p;
    __syncthreads();
    if (t < NCLS) {
        float sc = b_head[t];
        for (int f = 0; f < F; ++f) sc += pls[f] * w_head[f * NCLS + t];
        out[t] = sc;
    }
}

extern "C" void kernel_launch(void* const* d_in, const int* in_sizes, int n_in,
                              void* d_out, int out_size, void* d_ws, size_t ws_size,
                              hipStream_t stream) {
    const float* x       = (const float*)d_in[0];
    const int*   src     = (const int*)d_in[1];
    const int*   dst     = (const int*)d_in[2];
    const float* w_self0 = (const float*)d_in[3];
    const float* w_neigh0= (const float*)d_in[4];
    const float* b0      = (const float*)d_in[5];
    const float* w_self1 = (const float*)d_in[6];
    const float* w_neigh1= (const float*)d_in[7];
    const float* b1      = (const float*)d_in[8];
    const float* w_self2 = (const float*)d_in[9];
    const float* w_neigh2= (const float*)d_in[10];
    const float* b2      = (const float*)d_in[11];
    const float* w_head  = (const float*)d_in[12];
    const float* b_head  = (const float*)d_in[13];
    float* out = (float*)d_out;

    uint8_t* ws = (uint8_t*)d_ws;
    float* colsum   = (float*)(ws + OB_COLSUM);
    int*   bhist    = (int*)(ws + OB_BHIST);
    int*   bbase    = (int*)(ws + OB_BBASE);
    int*   bcur     = (int*)(ws + OB_BCUR);
    int*   row_start= (int*)(ws + OB_ROWSTART);
    float* inv_deg  = (float*)(ws + OB_INVDEG);
    uint32_t* pairs = (uint32_t*)(ws + OB_PAIRS);
    unsigned short* srcs16 = (unsigned short*)(ws + OB_SRCS16);
    uint8_t* wt     = ws + OB_WT;
    uint8_t* xb     = ws + OB_XB;     // doubles as hb2
    uint8_t* hb1    = ws + OB_HB1;
    uint8_t* nb     = ws + OB_NB;

    // zero colsum + bhist
    hipMemsetAsync(d_ws, 0, 1312, stream);

    convert_x_hist<<<6250, 256, 0, stream>>>(x, dst, xb, bhist);
    prep_w<<<dim3(32, 6), 256, 0, stream>>>(w_self0, w_neigh0, w_self1, w_neigh1,
                                            w_self2, w_neigh2, wt);
    bucket_scan<<<1, 256, 0, stream>>>(bhist, bbase, bcur, row_start);
    pass_a<<<3125, 256, 0, stream>>>(src, dst, bcur, pairs);
    pass_b<<<NB, 256, 0, stream>>>(pairs, bbase, row_start, inv_deg, srcs16);

    const int GB = (NN + 63) / 64;   // 782

    // layer 0: xb -> hb1
    aggregate_b<<<12500, 256, 0, stream>>>(xb, row_start, srcs16, inv_deg, nb);
    gemm_mfma<<<GB, 256, 0, stream>>>(xb, nb, wt + 0 * 32768, wt + 1 * 32768, b0, hb1, nullptr);
    // layer 1: hb1 -> xb (hb2 alias)
    aggregate_b<<<12500, 256, 0, stream>>>(hb1, row_start, srcs16, inv_deg, nb);
    gemm_mfma<<<GB, 256, 0, stream>>>(hb1, nb, wt + 2 * 32768, wt + 3 * 32768, b1, xb, nullptr);
    // layer 2: xb -> hb1, fused colsum
    aggregate_b<<<12500, 256, 0, stream>>>(xb, row_start, srcs16, inv_deg, nb);
    gemm_mfma<<<GB, 256, 0, stream>>>(xb, nb, wt + 4 * 32768, wt + 5 * 32768, b2, hb1, colsum);

    head_kernel<<<1, 128, 0, stream>>>(colsum, w_head, b_head, out);
}

// Round 4
// 220.105 us; speedup vs baseline: 4.9810x; 4.9810x over previous
//
#include <hip/hip_runtime.h>
#include <hip/hip_bf16.h>
#include <stdint.h>

#define NN 50000
#define NE 800000
#define F 128
#define NCLS 16
#define NB 196          // ceil(NN/256) buckets
#define BCAP 5120       // per-bucket capacity: mean 4096 + 16 sigma
#define PA_EPT 16       // edges per thread in pass_a

typedef __attribute__((ext_vector_type(8))) short short8;
typedef __attribute__((ext_vector_type(4))) float f32x4;
typedef __attribute__((ext_vector_type(4))) unsigned int uint4v;

// ---- ws byte offsets ----
#define OB_COLSUM    0u          // float[128]
#define OB_BCUR      512u        // int[196]
#define OB_BBASE     1536u       // int[196]
#define OB_ROWSTART  4096u       // int[50001]
#define OB_INVDEG    208896u     // float[50000]
#define OB_PAIRS     409600u     // u32[196*5120]
#define OB_SRCS16    4423680u    // u16[800000]
#define OB_WT        6023680u    // bf16 6*16384 (layout L)
#define OB_XB        6220800u    // bf16 [NN][128] layout L (doubles as HB2)
#define OB_HB1       19020800u
#define OB_NB2       31820800u   // ends 44620800

// ---- swizzled bf16 feature layout L ----
// element (row,k) at byte: row*256 + 16*(chunk(k) ^ (row&15)) + inchunk(k)
// chunk(k) = (k>>5)*4 | ((k>>2)&3); inchunk = ((k>>4)&1)*8 + (k&3)*2
__device__ __forceinline__ uint32_t swz_off(uint32_t row, uint32_t k) {
    uint32_t c = ((k >> 5) << 2) | ((k >> 2) & 3u);
    uint32_t b = (((k >> 4) & 1u) << 3) | ((k & 3u) << 1);
    return (row << 8) + (((c ^ (row & 15u)) << 4) | b);
}

__device__ __forceinline__ float bf_lo(uint32_t d) { return __uint_as_float(d << 16); }
__device__ __forceinline__ float bf_hi(uint32_t d) { return __uint_as_float(d & 0xffff0000u); }
__device__ __forceinline__ uint32_t pack_bf2(float a, float b) {
    __hip_bfloat16 l = __float2bfloat16(a), h = __float2bfloat16(b);
    return ((uint32_t)(*(uint16_t*)&h) << 16) | (uint32_t)(*(uint16_t*)&l);
}

// ====== init: zero colsum, set bucket cursors to bucket bases ======
__global__ void init_kernel(float* __restrict__ colsum, int* __restrict__ bcur) {
    int t = threadIdx.x;
    if (t < 128) colsum[t] = 0.f;
    if (t < NB) bcur[t] = t * BCAP;
}

// ====== convert x to bf16 layout L (float4/thread) ======
__global__ __launch_bounds__(256) void convert_x(const float* __restrict__ x,
                                                 uint8_t* __restrict__ xb) {
    int t = blockIdx.x * 256 + threadIdx.x;          // NN*32 quad-slots
    uint32_t row = (uint32_t)t >> 5;
    uint32_t q = (uint32_t)t & 31u;                  // 4-k group
    float4 v = *(const float4*)(x + row * F + q * 4);
    uint32_t c = ((q >> 3) << 2) | (q & 3u);
    uint32_t hi = (q >> 2) & 1u;
    uint2 pk;
    pk.x = pack_bf2(v.x, v.y);
    pk.y = pack_bf2(v.z, v.w);
    *(uint2*)(xb + (row << 8) + (((c ^ (row & 15u)) << 4) | (hi << 3))) = pk;
}

// transpose + convert weights: Wt[n][k] = W[k][n], layout L on (n,k)
__global__ __launch_bounds__(256) void prep_w(const float* __restrict__ w0, const float* __restrict__ w1,
                                              const float* __restrict__ w2, const float* __restrict__ w3,
                                              const float* __restrict__ w4, const float* __restrict__ w5,
                                              uint8_t* __restrict__ wt) {
    int m = blockIdx.y;
    const float* w = m == 0 ? w0 : m == 1 ? w1 : m == 2 ? w2 : m == 3 ? w3 : m == 4 ? w4 : w5;
    int t = blockIdx.x * 256 + threadIdx.x;          // 8192 pair-slots
    int n = t >> 6;
    int k0 = (t & 63) << 1;
    uint32_t pk = pack_bf2(w[k0 * F + n], w[(k0 + 1) * F + n]);
    *(uint32_t*)(wt + (uint32_t)m * 32768u + swz_off((uint32_t)n, (uint32_t)k0)) = pk;
}

// ====== pass A: LDS-aggregated scatter into fixed-capacity bucket streams ======
__global__ __launch_bounds__(256) void pass_a(const int* __restrict__ src,
                                              const int* __restrict__ dst,
                                              int* __restrict__ bcur,
                                              uint32_t* __restrict__ pairs) {
    __shared__ int cnt[NB];
    __shared__ int base_s[NB];
    int t = threadIdx.x;
    for (int i = t; i < NB; i += 256) cnt[i] = 0;
    __syncthreads();

    uint32_t pk[PA_EPT];
    int bk[PA_EPT];
    int e0 = blockIdx.x * (256 * PA_EPT) + t;
#pragma unroll
    for (int j = 0; j < PA_EPT; ++j) {
        int e = e0 + j * 256;
        if (e < NE) {
            int sv = src[e], dv = dst[e];
            bk[j] = dv >> 8;
            pk[j] = (uint32_t)sv | (((uint32_t)dv & 255u) << 16);
            atomicAdd(&cnt[bk[j]], 1);
        } else bk[j] = -1;
    }
    __syncthreads();
    // reserve ranges: <=196 global atomics per block
    for (int i = t; i < NB; i += 256) {
        if (cnt[i] > 0) base_s[i] = atomicAdd(&bcur[i], cnt[i]);
        cnt[i] = 0;   // reuse as local cursor
    }
    __syncthreads();
#pragma unroll
    for (int j = 0; j < PA_EPT; ++j) {
        if (bk[j] >= 0) {
            int pos = base_s[bk[j]] + atomicAdd(&cnt[bk[j]], 1);
            pairs[pos] = pk[j];
        }
    }
}

// ====== bucket base scan (196 fills -> contiguous CSR bases) ======
__global__ __launch_bounds__(256) void bucket_scan(const int* __restrict__ bcur,
                                                   int* __restrict__ bbase,
                                                   int* __restrict__ row_start) {
    __shared__ int s[256];
    int t = threadIdx.x;
    int fill = (t < NB) ? (bcur[t] - t * BCAP) : 0;
    s[t] = fill;
    __syncthreads();
    for (int off = 1; off < 256; off <<= 1) {
        int u = (t >= off) ? s[t - off] : 0;
        __syncthreads();
        s[t] += u;
        __syncthreads();
    }
    if (t < NB) bbase[t] = s[t] - fill;   // exclusive
    if (t == 0) row_start[NN] = NE;
}

// ====== pass B: per-bucket count/scan, emit row_start+inv_deg+srcs16 ======
__global__ __launch_bounds__(256) void pass_b(const uint32_t* __restrict__ pairs,
                                              const int* __restrict__ bcur,
                                              const int* __restrict__ bbase,
                                              int* __restrict__ row_start,
                                              float* __restrict__ inv_deg,
                                              unsigned short* __restrict__ srcs) {
    __shared__ int cnt[256];
    __shared__ int s[256];
    __shared__ int cur[256];
    int b = blockIdx.x, t = threadIdx.x;
    int in0 = b * BCAP;
    int fill = bcur[b] - in0;
    int out0 = bbase[b];
    cnt[t] = 0;
    __syncthreads();
    for (int i = t; i < fill; i += 256)
        atomicAdd(&cnt[pairs[in0 + i] >> 16], 1);
    __syncthreads();
    int v = cnt[t];
    s[t] = v;
    __syncthreads();
    for (int off = 1; off < 256; off <<= 1) {
        int u = (t >= off) ? s[t - off] : 0;
        __syncthreads();
        s[t] += u;
        __syncthreads();
    }
    int excl = s[t] - v;
    cur[t] = out0 + excl;
    int row = (b << 8) + t;
    if (row < NN) {
        row_start[row] = out0 + excl;
        inv_deg[row] = 1.0f / (float)(v > 1 ? v : 1);
    }
    __syncthreads();
    for (int i = t; i < fill; i += 256) {
        uint32_t p = pairs[in0 + i];
        int pos = atomicAdd(&cur[p >> 16], 1);
        srcs[pos] = (unsigned short)(p & 0xffffu);
    }
}

// ====== aggregate: one wave per node, 2 edges/iter, dwordx2 gathers ======
__global__ __launch_bounds__(256) void aggregate_b(
        const uint8_t* __restrict__ hb, const int* __restrict__ row_start,
        const unsigned short* __restrict__ srcs, const float* __restrict__ inv_deg,
        uint8_t* __restrict__ nb) {
    int node = blockIdx.x * 4 + (threadIdx.x >> 6);
    int l = threadIdx.x & 63;
    int half = l >> 5;
    uint32_t sub = (uint32_t)(l & 31);
    uint32_t c_lin = sub & 15u;
    uint32_t boff = (sub >> 4) << 3;
    int e0 = row_start[node], e1 = row_start[node + 1];
    float a0 = 0.f, a1 = 0.f, a2 = 0.f, a3 = 0.f;

#define LDROW(S) (*(const uint2*)(hb + ((uint32_t)(S) << 8) + (((c_lin ^ ((uint32_t)(S) & 15u)) << 4) | boff)))
    int e = e0 + half;
    for (; e + 6 < e1; e += 8) {
        uint32_t s0 = srcs[e], s1 = srcs[e + 2], s2 = srcs[e + 4], s3 = srcs[e + 6];
        uint2 d0 = LDROW(s0);
        uint2 d1 = LDROW(s1);
        uint2 d2 = LDROW(s2);
        uint2 d3 = LDROW(s3);
        a0 += bf_lo(d0.x) + bf_lo(d1.x) + bf_lo(d2.x) + bf_lo(d3.x);
        a1 += bf_hi(d0.x) + bf_hi(d1.x) + bf_hi(d2.x) + bf_hi(d3.x);
        a2 += bf_lo(d0.y) + bf_lo(d1.y) + bf_lo(d2.y) + bf_lo(d3.y);
        a3 += bf_hi(d0.y) + bf_hi(d1.y) + bf_hi(d2.y) + bf_hi(d3.y);
    }
    for (; e < e1; e += 2) {
        uint32_t s0 = srcs[e];
        uint2 d0 = LDROW(s0);
        a0 += bf_lo(d0.x); a1 += bf_hi(d0.x); a2 += bf_lo(d0.y); a3 += bf_hi(d0.y);
    }
#undef LDROW
    a0 += __shfl_xor(a0, 32);
    a1 += __shfl_xor(a1, 32);
    a2 += __shfl_xor(a2, 32);
    a3 += __shfl_xor(a3, 32);
    if (half == 0) {
        float idg = inv_deg[node];
        uint2 pk;
        pk.x = pack_bf2(a0 * idg, a1 * idg);
        pk.y = pack_bf2(a2 * idg, a3 * idg);
        *(uint2*)(nb + ((uint32_t)node << 8) +
                  (((c_lin ^ ((uint32_t)node & 15u)) << 4) | boff)) = pk;
    }
}

// ====== MFMA GEMM: hout = relu(As@Ws + An@Wn + b); optional colsum fuse ======
__global__ __launch_bounds__(256) void gemm_mfma(
        const uint8_t* __restrict__ a_self, const uint8_t* __restrict__ a_neigh,
        const uint8_t* __restrict__ wt_self, const uint8_t* __restrict__ wt_neigh,
        const float* __restrict__ bias, uint8_t* __restrict__ hout,
        float* colsum) {
    __shared__ uint4v As4[1024];   // 16 KB
    __shared__ uint4v Ws4[2048];   // 32 KB
    __shared__ float cs[128];
    int tid = threadIdx.x;
    int lane = tid & 63, wave = tid >> 6;
    int rl = lane & 15, g = lane >> 4;
    int row0 = blockIdx.x * 64;

    f32x4 acc[8];
    f32x4 z = {0.f, 0.f, 0.f, 0.f};
#pragma unroll
    for (int nt = 0; nt < 8; ++nt) acc[nt] = z;

    const char* AsB = (const char*)As4;
    const char* WsB = (const char*)Ws4;

#pragma unroll
    for (int pass = 0; pass < 2; ++pass) {
        if (pass) __syncthreads();
        const uint4v* ga = (const uint4v*)((pass ? a_neigh : a_self) + (size_t)row0 * 256);
        const uint4v* gw = (const uint4v*)(pass ? wt_neigh : wt_self);
#pragma unroll
        for (int i = 0; i < 4; ++i) As4[tid + i * 256] = ga[tid + i * 256];
#pragma unroll
        for (int i = 0; i < 8; ++i) Ws4[tid + i * 256] = gw[tid + i * 256];
        __syncthreads();
#pragma unroll
        for (int ks = 0; ks < 4; ++ks) {
            int chunk = ((ks << 2) | g) ^ rl;
            short8 a = *(const short8*)(AsB + ((wave * 16 + rl) << 8) + (chunk << 4));
#pragma unroll
            for (int nt = 0; nt < 8; ++nt) {
                short8 bb = *(const short8*)(WsB + ((nt * 16 + rl) << 8) + (chunk << 4));
                acc[nt] = __builtin_amdgcn_mfma_f32_16x16x32_bf16(a, bb, acc[nt], 0, 0, 0);
            }
        }
    }

    bool doCol = (colsum != nullptr);
    if (doCol) {
        if (tid < 128) cs[tid] = 0.f;
        __syncthreads();
    }
#pragma unroll
    for (int nt = 0; nt < 8; ++nt) {
        int col = nt * 16 + rl;
        float bv = bias[col];
        float rsum = 0.f;
#pragma unroll
        for (int i = 0; i < 4; ++i) {
            int row = row0 + wave * 16 + g * 4 + i;
            if (row < NN) {
                float v = fmaxf(acc[nt][i] + bv, 0.f);
                rsum += v;
                *(__hip_bfloat16*)(hout + swz_off((uint32_t)row, (uint32_t)col)) =
                    __float2bfloat16(v);
            }
        }
        if (doCol) atomicAdd(&cs[col], rsum);
    }
    if (doCol) {
        __syncthreads();
        if (tid < 128) atomicAdd(&colsum[tid], cs[tid]);
    }
}

__global__ __launch_bounds__(128) void head_kernel(const float* __restrict__ colsum,
                                                   const float* __restrict__ w_head,
                                                   const float* __restrict__ b_head,
                                                   float* __restrict__ out) {
    __shared__ float pls[F];
    int t = threadIdx.x;
    float p = colsum[t] * (1.0f / (float)NN);
    pls[t] = p;
    out[NCLS + t] = p;
    __syncthreads();
    if (t < NCLS) {
        float sc = b_head[t];
        for (int f = 0; f < F; ++f) sc += pls[f] * w_head[f * NCLS + t];
        out[t] = sc;
    }
}

extern "C" void kernel_launch(void* const* d_in, const int* in_sizes, int n_in,
                              void* d_out, int out_size, void* d_ws, size_t ws_size,
                              hipStream_t stream) {
    const float* x       = (const float*)d_in[0];
    const int*   src     = (const int*)d_in[1];
    const int*   dst     = (const int*)d_in[2];
    const float* w_self0 = (const float*)d_in[3];
    const float* w_neigh0= (const float*)d_in[4];
    const float* b0      = (const float*)d_in[5];
    const float* w_self1 = (const float*)d_in[6];
    const float* w_neigh1= (const float*)d_in[7];
    const float* b1      = (const float*)d_in[8];
    const float* w_self2 = (const float*)d_in[9];
    const float* w_neigh2= (const float*)d_in[10];
    const float* b2      = (const float*)d_in[11];
    const float* w_head  = (const float*)d_in[12];
    const float* b_head  = (const float*)d_in[13];
    float* out = (float*)d_out;

    uint8_t* ws = (uint8_t*)d_ws;
    float* colsum   = (float*)(ws + OB_COLSUM);
    int*   bcur     = (int*)(ws + OB_BCUR);
    int*   bbase    = (int*)(ws + OB_BBASE);
    int*   row_start= (int*)(ws + OB_ROWSTART);
    float* inv_deg  = (float*)(ws + OB_INVDEG);
    uint32_t* pairs = (uint32_t*)(ws + OB_PAIRS);
    unsigned short* srcs16 = (unsigned short*)(ws + OB_SRCS16);
    uint8_t* wt     = ws + OB_WT;
    uint8_t* xb     = ws + OB_XB;     // doubles as hb2
    uint8_t* hb1    = ws + OB_HB1;
    uint8_t* nb     = ws + OB_NB2;

    init_kernel<<<1, 256, 0, stream>>>(colsum, bcur);
    convert_x<<<6250, 256, 0, stream>>>(x, xb);
    prep_w<<<dim3(32, 6), 256, 0, stream>>>(w_self0, w_neigh0, w_self1, w_neigh1,
                                            w_self2, w_neigh2, wt);
    pass_a<<<NB, 256, 0, stream>>>(src, dst, bcur, pairs);
    bucket_scan<<<1, 256, 0, stream>>>(bcur, bbase, row_start);
    pass_b<<<NB, 256, 0, stream>>>(pairs, bcur, bbase, row_start, inv_deg, srcs16);

    const int GB = (NN + 63) / 64;   // 782

    // layer 0: xb -> hb1
    aggregate_b<<<12500, 256, 0, stream>>>(xb, row_start, srcs16, inv_deg, nb);
    gemm_mfma<<<GB, 256, 0, stream>>>(xb, nb, wt + 0 * 32768, wt + 1 * 32768, b0, hb1, nullptr);
    // layer 1: hb1 -> xb (hb2 alias)
    aggregate_b<<<12500, 256, 0, stream>>>(hb1, row_start, srcs16, inv_deg, nb);
    gemm_mfma<<<GB, 256, 0, stream>>>(hb1, nb, wt + 2 * 32768, wt + 3 * 32768, b1, xb, nullptr);
    // layer 2: xb -> hb1, fused colsum
    aggregate_b<<<12500, 256, 0, stream>>>(xb, row_start, srcs16, inv_deg, nb);
    gemm_mfma<<<GB, 256, 0, stream>>>(xb, nb, wt + 4 * 32768, wt + 5 * 32768, b2, hb1, colsum);

    head_kernel<<<1, 128, 0, stream>>>(colsum, w_head, b_head, out);
}